// Round 10
// baseline (582.836 us; speedup 1.0000x reference)
//
#include <hip/hip_runtime.h>

static constexpr int T_LEN = 512;

typedef float v4f __attribute__((ext_vector_type(4)));
typedef _Float16 v8h __attribute__((ext_vector_type(8)));
typedef _Float16 hh2 __attribute__((ext_vector_type(2)));

union H8 { v8h v; hh2 p[4]; };

__device__ __forceinline__ float fsigm(float x) {
    return __builtin_amdgcn_rcpf(1.0f + __expf(-x));
}
__device__ __forceinline__ float ftanh(float x) {
    return 1.0f - 2.0f * __builtin_amdgcn_rcpf(1.0f + __expf(2.0f * x));
}
__device__ __forceinline__ hh2 pk16(float a, float b) {
    return __builtin_bit_cast(hh2, __builtin_amdgcn_cvt_pkrtz(a, b));
}
__device__ __forceinline__ v4f mfma(v8h a, v8h b, v4f c) {
    return __builtin_amdgcn_mfma_f32_16x16x32_f16(a, b, c, 0, 0, 0);
}

// ONE wave = 16 batches, BOTH layers, x-GEMM folded in. No LDS, no barriers,
// no workspace. Per step: 10 MFMA (16x16x32 f16) + gate VALU + 12 shfl_xor
// fragment exchange. State h0,h1 stay fp32 (D layout); only MFMA operands
// are f16-quantized.
//
// Layouts (16x16x32): A[row][k]: row=l&15, k=(l>>4)*8+i (8 f16/lane)
//                     B[k][col]: col=l&15, k=(l>>4)*8+i
//                     D[row][col]: col=l&15, row=(l>>4)*4+i (4 f32/lane) [verified]
// Gate matvecs: D[unit][batch] = W[unit][k] * S[k][batch].
//   L0: pre = Wih0*x[t] (K=32) + Whh0*[h0;0] (K=32, hi half zero)
//   L1: pre = [Wih1|Whh1] * [h0[t]; h1[t-1]] (K=32); n-gate split into
//       xn=[Wih1_n|0]*S and hn=[0|Whh1_n]*S to keep r*hn structure.
__global__ __launch_bounds__(64, 1) void gru2_mfma(
    const float* __restrict__ x,
    const float* __restrict__ Wih0, const float* __restrict__ Whh0,
    const float* __restrict__ bih0, const float* __restrict__ bhh0,
    const float* __restrict__ Wih1, const float* __restrict__ Whh1,
    const float* __restrict__ bih1, const float* __restrict__ bhh1,
    const float* __restrict__ fcw,  const float* __restrict__ fcb,
    float* __restrict__ out)
{
    const int l  = threadIdx.x;   // 0..63
    const int c  = l & 15;        // A-row (unit) / B-col (batch) owner index
    const int g  = l >> 4;        // k-octet group (0..3)
    const int k0 = g * 8;
    const int b0 = blockIdx.x * 16;

    // ---- weight A-fragments (f16), loaded once ----
    H8 A_x[3], A_h[3], A_rz[2], A_xn, A_hn;
#pragma unroll
    for (int g3 = 0; g3 < 3; ++g3) {
        const int row = g3 * 16 + c;
#pragma unroll
        for (int q = 0; q < 4; ++q) {
            // Wih0: full K=32
            A_x[g3].p[q] = pk16(Wih0[row * 32 + k0 + 2 * q],
                                Wih0[row * 32 + k0 + 2 * q + 1]);
            // Whh0: K=16 in low half, zeros in high half
            float w0 = (g < 2) ? Whh0[row * 16 + k0 + 2 * q]     : 0.f;
            float w1 = (g < 2) ? Whh0[row * 16 + k0 + 2 * q + 1] : 0.f;
            A_h[g3].p[q] = pk16(w0, w1);
        }
    }
#pragma unroll
    for (int j = 0; j < 2; ++j) {   // r-rows, z-rows of layer 1
        const int row = j * 16 + c;
#pragma unroll
        for (int q = 0; q < 4; ++q) {
            float w0 = (g < 2) ? Wih1[row * 16 + k0 + 2 * q]
                               : Whh1[row * 16 + (k0 - 16) + 2 * q];
            float w1 = (g < 2) ? Wih1[row * 16 + k0 + 2 * q + 1]
                               : Whh1[row * 16 + (k0 - 16) + 2 * q + 1];
            A_rz[j].p[q] = pk16(w0, w1);
        }
    }
    {
        const int row = 32 + c;   // n-rows of layer 1
#pragma unroll
        for (int q = 0; q < 4; ++q) {
            float a0 = (g < 2) ? Wih1[row * 16 + k0 + 2 * q]     : 0.f;
            float a1 = (g < 2) ? Wih1[row * 16 + k0 + 2 * q + 1] : 0.f;
            A_xn.p[q] = pk16(a0, a1);
            float h0w = (g >= 2) ? Whh1[row * 16 + (k0 - 16) + 2 * q]     : 0.f;
            float h1w = (g >= 2) ? Whh1[row * 16 + (k0 - 16) + 2 * q + 1] : 0.f;
            A_hn.p[q] = pk16(h0w, h1w);
        }
    }

    // ---- bias C-fragments (f32, D layout: row = g*4+i) ----
    v4f Cr0, Cz0, Cxn0, Chn0, Cr1, Cz1, Cxn1, Chn1;
#pragma unroll
    for (int i = 0; i < 4; ++i) {
        const int rc = g * 4 + i;
        Cr0[i]  = bih0[rc]      + bhh0[rc];
        Cz0[i]  = bih0[16 + rc] + bhh0[16 + rc];
        Cxn0[i] = bih0[32 + rc];
        Chn0[i] = bhh0[32 + rc];
        Cr1[i]  = bih1[rc]      + bhh1[rc];
        Cz1[i]  = bih1[16 + rc] + bhh1[16 + rc];
        Cxn1[i] = bih1[32 + rc];
        Chn1[i] = bhh1[32 + rc];
    }
    float fw4[4];
#pragma unroll
    for (int i = 0; i < 4; ++i) fw4[i] = fcw[g * 4 + i];

    // ---- state (fp32, D layout) ----
    float h0s[4] = {0.f, 0.f, 0.f, 0.f};
    float h1s[4] = {0.f, 0.f, 0.f, 0.f};
    const hh2 z2 = pk16(0.f, 0.f);
    H8 Sh0;  // B-frag [h0; 0]
#pragma unroll
    for (int q = 0; q < 4; ++q) Sh0.p[q] = z2;

    // ---- x prefetch ring: 4 steps deep, 8 f32/lane/step ----
    const float* xp = x + ((size_t)(b0 + c) * T_LEN) * 32 + k0;
    float4 ra0, rb0, ra1, rb1, ra2, rb2, ra3, rb3;
    ra0 = *(const float4*)(xp + 0 * 32);  rb0 = *(const float4*)(xp + 0 * 32 + 4);
    ra1 = *(const float4*)(xp + 1 * 32);  rb1 = *(const float4*)(xp + 1 * 32 + 4);
    ra2 = *(const float4*)(xp + 2 * 32);  rb2 = *(const float4*)(xp + 2 * 32 + 4);
    ra3 = *(const float4*)(xp + 3 * 32);  rb3 = *(const float4*)(xp + 3 * 32 + 4);

    auto step = [&](float4& ra, float4& rb, int t) {
        // x B-fragment for step t
        H8 xB;
        xB.p[0] = pk16(ra.x, ra.y);
        xB.p[1] = pk16(ra.z, ra.w);
        xB.p[2] = pk16(rb.x, rb.y);
        xB.p[3] = pk16(rb.z, rb.w);
        // prefetch t+4
        const int t4 = (t + 4 < T_LEN) ? (t + 4) : (T_LEN - 1);
        ra = *(const float4*)(xp + (size_t)t4 * 32);
        rb = *(const float4*)(xp + (size_t)t4 * 32 + 4);

        // ---- layer 0: pre-gates via MFMA ----
        v4f rD  = mfma(A_x[0].v, xB.v, Cr0);
        rD      = mfma(A_h[0].v, Sh0.v, rD);
        v4f zD  = mfma(A_x[1].v, xB.v, Cz0);
        zD      = mfma(A_h[1].v, Sh0.v, zD);
        v4f xnD = mfma(A_x[2].v, xB.v, Cxn0);
        v4f hnD = mfma(A_h[2].v, Sh0.v, Chn0);

        // ---- layer-0 gates (4 units/lane), state stays fp32 ----
        float a4[4], b4[4];
#pragma unroll
        for (int i = 0; i < 4; ++i) {
            const float r = fsigm(rD[i]);
            const float z = fsigm(zD[i]);
            const float n = ftanh(xnD[i] + r * hnD[i]);
            h0s[i] = fmaf(z, h0s[i] - n, n);
            a4[i] = h0s[i];     // h0[t]
            b4[i] = h1s[i];     // h1[t-1] (pre-update)
        }

        // ---- exchange: D layout (4 units/lane) -> B layout (8 k/lane) ----
        float u1[4], u2[4], u3[4], lo[4], hi[4];
#pragma unroll
        for (int i = 0; i < 4; ++i)
            u1[i] = __shfl_xor((g & 2) ? b4[i] : a4[i], 16, 64);
#pragma unroll
        for (int i = 0; i < 4; ++i)
            u2[i] = __shfl_xor((g & 1) ? a4[i] : b4[i], 32, 64);
#pragma unroll
        for (int i = 0; i < 4; ++i)
            u3[i] = __shfl_xor((g & 2) ? a4[i] : b4[i], 48, 64);
#pragma unroll
        for (int i = 0; i < 4; ++i) {
            lo[i] = (g == 0) ? a4[i] : (g == 1) ? u3[i] : (g == 2) ? u2[i] : u1[i];
            hi[i] = (g == 0) ? u1[i] : (g == 1) ? u2[i] : (g == 2) ? u3[i] : b4[i];
        }
        H8 S1;   // [h0[t]; h1[t-1]]
        S1.p[0] = pk16(lo[0], lo[1]);
        S1.p[1] = pk16(lo[2], lo[3]);
        S1.p[2] = pk16(hi[0], hi[1]);
        S1.p[3] = pk16(hi[2], hi[3]);
        // next step's L0 h-frag: [h0[t]; 0]
#pragma unroll
        for (int q = 0; q < 4; ++q)
            Sh0.p[q] = (g < 2) ? S1.p[q] : z2;

        // ---- layer 1 ----
        v4f r1D  = mfma(A_rz[0].v, S1.v, Cr1);
        v4f z1D  = mfma(A_rz[1].v, S1.v, Cz1);
        v4f xn1D = mfma(A_xn.v,   S1.v, Cxn1);
        v4f hn1D = mfma(A_hn.v,   S1.v, Chn1);
#pragma unroll
        for (int i = 0; i < 4; ++i) {
            const float r = fsigm(r1D[i]);
            const float z = fsigm(z1D[i]);
            const float n = ftanh(xn1D[i] + r * hn1D[i]);
            h1s[i] = fmaf(z, h1s[i] - n, n);
        }
    };

#pragma unroll 1
    for (int t = 0; t < T_LEN; t += 4) {
        step(ra0, rb0, t);
        step(ra1, rb1, t + 1);
        step(ra2, rb2, t + 2);
        step(ra3, rb3, t + 3);
    }

    // ---- FC on final h1: out[b] = fcw . h1[:,b] + fcb ----
    float p = 0.f;
#pragma unroll
    for (int i = 0; i < 4; ++i) p = fmaf(fw4[i], h1s[i], p);
    p += __shfl_xor(p, 16, 64);
    p += __shfl_xor(p, 32, 64);
    if (l < 16) out[b0 + l] = p + fcb[0];
}

extern "C" void kernel_launch(void* const* d_in, const int* in_sizes, int n_in,
                              void* d_out, int out_size, void* d_ws, size_t ws_size,
                              hipStream_t stream) {
    const float* x    = (const float*)d_in[0];
    const float* Wih0 = (const float*)d_in[1];
    const float* Whh0 = (const float*)d_in[2];
    const float* bih0 = (const float*)d_in[3];
    const float* bhh0 = (const float*)d_in[4];
    const float* Wih1 = (const float*)d_in[5];
    const float* Whh1 = (const float*)d_in[6];
    const float* bih1 = (const float*)d_in[7];
    const float* bhh1 = (const float*)d_in[8];
    const float* fcw  = (const float*)d_in[9];
    const float* fcb  = (const float*)d_in[10];

    // 2048 batches / 16 per wave = 128 single-wave blocks
    gru2_mfma<<<128, 64, 0, stream>>>(x, Wih0, Whh0, bih0, bhh0,
                                      Wih1, Whh1, bih1, bhh1, fcw, fcb,
                                      (float*)d_out);
}

// Round 11
// 256.985 us; speedup vs baseline: 2.2680x; 2.2680x over previous
//
#include <hip/hip_runtime.h>

static constexpr int T_LEN = 512;
// packed fp16 xg workspace: per (b,t) row = 96 B: [0,64) = (r,z) hh2 pairs
// (4B per j), [64,96) = n halves (2B per j). +pad for tail prefetch.
static constexpr size_t XG16_BYTES = (size_t)2048 * T_LEN * 96;
static constexpr size_t WS_NEEDED  = XG16_BYTES + 4096;

typedef float v2f __attribute__((ext_vector_type(2)));
typedef _Float16 hh2 __attribute__((ext_vector_type(2)));

__device__ __forceinline__ float fsigm(float x) {
    return __builtin_amdgcn_rcpf(1.0f + __expf(-x));
}
__device__ __forceinline__ float ftanh(float x) {
    return 1.0f - 2.0f * __builtin_amdgcn_rcpf(1.0f + __expf(2.0f * x));
}
template <int CTRL>
__device__ __forceinline__ float rotf(float v) {
    return __builtin_bit_cast(float,
        __builtin_amdgcn_mov_dpp(__builtin_bit_cast(int, v), CTRL, 0xf, 0xf, true));
}
__device__ __forceinline__ void pk_acc(v2f& acc, v2f a, v2f b) {
    asm("v_pk_fma_f32 %0, %1, %2, %0" : "+v"(acc) : "v"(a), "v"(b));
}
__device__ __forceinline__ hh2 pk16(float a, float b) {
    return __builtin_bit_cast(hh2, __builtin_amdgcn_cvt_pkrtz(a, b));
}

// ---------------- Phase A: xg = fp16(x @ W_ih0^T + b_ih0), packed layout ----
__global__ __launch_bounds__(256) void xg_gemm16(
    const float* __restrict__ x, const float* __restrict__ Wih0,
    const float* __restrict__ bih0, void* __restrict__ xg)
{
    const int tid  = threadIdx.x;
    const int lane = tid & 63;
    const int j    = lane & 15;
    const int q    = lane >> 4;
    const int wv   = blockIdx.x * 4 + (tid >> 6);

    const int d1 = (((int)rotf<0x121>((float)j)) - j) & 15;

    v2f W0[16], W1[16], W2[16];
#pragma unroll
    for (int m = 0; m < 16; ++m) {
        const int cm = (j + m * d1) & 15;
        W0[m].x = Wih0[(0*16+j)*32 + cm]; W0[m].y = Wih0[(0*16+j)*32 + 16 + cm];
        W1[m].x = Wih0[(1*16+j)*32 + cm]; W1[m].y = Wih0[(1*16+j)*32 + 16 + cm];
        W2[m].x = Wih0[(2*16+j)*32 + cm]; W2[m].y = Wih0[(2*16+j)*32 + 16 + cm];
    }
    const float b0 = bih0[j], b1 = bih0[16 + j], b2 = bih0[32 + j];

    const size_t row0 = (size_t)wv * 1024 + q;   // rows row0 + 4t, t=0..255
    const float* xl = x + row0 * 32 + j;
    char* ob = (char*)xg + row0 * 96;

    float xa0 = xl[0*128], xb0 = xl[0*128+16];
    float xa1 = xl[1*128], xb1 = xl[1*128+16];
    float xa2 = xl[2*128], xb2 = xl[2*128+16];
    float xa3 = xl[3*128], xb3 = xl[3*128+16];

    auto doRow = [&](float& xa, float& xb, int t) {
        v2f p; p.x = xa; p.y = xb;
        const int t4 = (t + 4 < 256) ? (t + 4) : 255;
        xa = xl[(size_t)t4 * 128];
        xb = xl[(size_t)t4 * 128 + 16];
        v2f a0 = {0.f,0.f}, a1 = {0.f,0.f}, a2 = {0.f,0.f};
#pragma unroll
        for (int m = 0; m < 16; ++m) {
            pk_acc(a0, W0[m], p);
            pk_acc(a1, W1[m], p);
            pk_acc(a2, W2[m], p);
            if (m < 15) { p.x = rotf<0x121>(p.x); p.y = rotf<0x121>(p.y); }
        }
        const float r = a0.x + a0.y + b0;
        const float z = a1.x + a1.y + b1;
        const float n = a2.x + a2.y + b2;
        *(hh2*)(ob + (size_t)t*384 + 4*j) = pk16(r, z);
        *(unsigned short*)(ob + (size_t)t*384 + 64 + 2*j) =
            __builtin_bit_cast(unsigned short, (_Float16)n);
    };
#pragma unroll 1
    for (int t = 0; t < 256; t += 4) {
        doRow(xa0, xb0, t);
        doRow(xa1, xb1, t + 1);
        doRow(xa2, xb2, t + 2);
        doRow(xa3, xb3, t + 3);
    }
}

// ---------------- Phase B: recurrence (R9 layout + addr-bump + weight pin) --
// Lanes: j=lane&15 (unit), role=bit4 (0:L0, 1:L1 one step behind), bq=bit5
// (batch). 1024 waves. ONE shuffle/step. 48 v_pk_fma_f32 per step (2 batches,
// both layers). Changes vs R9: (1) weights pinned via opaque asm -> must stay
// register-resident; (2) pointer-bump addressing, loads with imm offsets,
// no clamp (ws padded); (3) packed xg: 1 dword (r,z) + 1 ushort (n) per step.
__global__ __launch_bounds__(256, 1) void gru2_v2(
    const void* __restrict__ xg,
    const float* __restrict__ Whh0, const float* __restrict__ bhh0,
    const float* __restrict__ Wih1, const float* __restrict__ Whh1,
    const float* __restrict__ bih1, const float* __restrict__ bhh1,
    const float* __restrict__ fcw,  const float* __restrict__ fcb,
    float* __restrict__ out)
{
    const int tid  = threadIdx.x;
    const int lane = tid & 63;
    const int j    = lane & 15;
    const int role = (lane >> 4) & 1;
    const int bq   = lane >> 5;
    const int b    = blockIdx.x * 8 + (tid >> 6) * 2 + bq;

    const int d1 = (((int)rotf<0x121>((float)j)) - j) & 15;

    v2f WA[3][16];
    float B_r, B_z, B_in, B_hn, rmask;
#pragma unroll
    for (int g = 0; g < 3; ++g) {
        const int row = g * 16 + j;
#pragma unroll
        for (int m = 0; m < 16; ++m) {
            const int cm = (j + m * d1) & 15;
            if (role) {
                WA[g][m].x = Wih1[row * 16 + cm];
                WA[g][m].y = Whh1[row * 16 + cm];
            } else {
                const float w = Whh0[row * 16 + cm];
                WA[g][m].x = (g == 2) ? 0.f : w;
                WA[g][m].y = (g == 2) ? w : 0.f;
            }
            // PIN: opaque def -> compiler cannot rematerialize the load into
            // the loop; value must stay in a register (spill would be visible
            // as scratch traffic).
            asm volatile("" : "+v"(WA[g][m]));
        }
    }
    if (role) {
        B_r = bih1[j] + bhh1[j];  B_z = bih1[16 + j] + bhh1[16 + j];
        B_in = bih1[32 + j];      B_hn = bhh1[32 + j];  rmask = 0.f;
    } else {
        B_r = bhh0[j];  B_z = bhh0[16 + j];
        B_in = 0.f;     B_hn = bhh0[32 + j];            rmask = 1.f;
    }

    float hs = 0.f;   // role0: h0_j ; role1: h1_j

    // byte-base pointers, bumped +384 per 4-step group; loads use imm offsets
    const char* pb = (const char*)xg + (size_t)b * T_LEN * 96;
    const char* rzp = pb + 4 * j;
    const char* np  = pb + 64 + 2 * j;

    // 4-deep ring of RAW loaded values (cvt at use)
    unsigned rz0 = *(const unsigned*)(rzp +   0);
    unsigned rz1 = *(const unsigned*)(rzp +  96);
    unsigned rz2 = *(const unsigned*)(rzp + 192);
    unsigned rz3 = *(const unsigned*)(rzp + 288);
    unsigned nn0 = *(const unsigned short*)(np +   0);
    unsigned nn1 = *(const unsigned short*)(np +  96);
    unsigned nn2 = *(const unsigned short*)(np + 192);
    unsigned nn3 = *(const unsigned short*)(np + 288);
    rzp += 384; np += 384;

    auto step = [&](unsigned& RZ, unsigned& NN, int pfo, bool pf) {
        const float us = __shfl_xor(hs, 16, 64);

        const hh2 rzh = __builtin_bit_cast(hh2, RZ);
        const float Xr = (float)rzh[0] * rmask;
        const float Xz = (float)rzh[1] * rmask;
        const float Xn = (float)__builtin_bit_cast(_Float16,
                              (unsigned short)NN) * rmask;
        if (pf) {
            RZ = *(const unsigned*)(rzp + pfo);
            NN = *(const unsigned short*)(np + pfo);
        }

        v2f p;
        p.x = role ? us : hs;
        p.y = hs;
        v2f a0 = {0.f,0.f}, a1 = {0.f,0.f}, a2 = {0.f,0.f};
#pragma unroll
        for (int m = 0; m < 16; ++m) {
            pk_acc(a0, WA[0][m], p);
            pk_acc(a1, WA[1][m], p);
            pk_acc(a2, WA[2][m], p);
            if (m < 15) { p.x = rotf<0x121>(p.x); p.y = rotf<0x121>(p.y); }
        }

        const float r = fsigm(Xr + a0.x + a0.y + B_r);
        const float z = fsigm(Xz + a1.x + a1.y + B_z);
        const float n = ftanh(Xn + a2.x + B_in + r * (a2.y + B_hn));
        hs = fmaf(z, hs - n, n);
    };

    // peeled group 0: steps 0..3 (reset role1 after step 0)
    step(rz0, nn0,   0, true);
    hs = role ? 0.f : hs;
    step(rz1, nn1,  96, true);
    step(rz2, nn2, 192, true);
    step(rz3, nn3, 288, true);
    rzp += 384; np += 384;

    // groups 1..127: steps 4g..4g+3; prefetch rows 4g+4..4g+7
#pragma unroll 1
    for (int g = 1; g < 128; ++g) {
        step(rz0, nn0,   0, true);
        step(rz1, nn1,  96, true);
        step(rz2, nn2, 192, true);
        step(rz3, nn3, 288, true);
        rzp += 384; np += 384;
    }

    // epilogue step i=512: role1 computes h1[511]; role0 phantom (discarded)
    step(rz0, nn0, 0, false);

    // FC on final h1 (role1 lanes hold it distributed)
    if (role) {
        float pfc = fcw[j] * hs;
        pfc += __shfl_xor(pfc, 1, 64);
        pfc += __shfl_xor(pfc, 2, 64);
        pfc += __shfl_xor(pfc, 4, 64);
        pfc += __shfl_xor(pfc, 8, 64);
        if (j == 0) out[b] = pfc + fcb[0];
    }
}

// ---------------- Fallback (R9 fused kernel): used when ws is too small ----
__global__ __launch_bounds__(256, 1) void gru2_merged(
    const float* __restrict__ x,
    const float* __restrict__ Wih0, const float* __restrict__ Whh0,
    const float* __restrict__ bih0, const float* __restrict__ bhh0,
    const float* __restrict__ Wih1, const float* __restrict__ Whh1,
    const float* __restrict__ bih1, const float* __restrict__ bhh1,
    const float* __restrict__ fcw,  const float* __restrict__ fcb,
    float* __restrict__ out)
{
    const int tid  = threadIdx.x;
    const int lane = tid & 63;
    const int j    = lane & 15;
    const int role = (lane >> 4) & 1;
    const int bq   = lane >> 5;
    const int b    = blockIdx.x * 8 + (tid >> 6) * 2 + bq;

    const int d1 = (((int)rotf<0x121>((float)j)) - j) & 15;
    const int d2 = (((int)rotf<0x122>((float)j)) - j) & 15;

    v2f WA[3][16];
    v2f WB[3][8];
    float b_r, b_z, b_in, b_hn;
#pragma unroll
    for (int g = 0; g < 3; ++g) {
        const int row = g * 16 + j;
#pragma unroll
        for (int m = 0; m < 16; ++m) {
            const int cm = (j + m * d1) & 15;
            if (role) {
                WA[g][m].x = Wih1[row * 16 + cm];
                WA[g][m].y = Whh1[row * 16 + cm];
            } else {
                WA[g][m].x = Wih0[row * 32 + cm];
                WA[g][m].y = Wih0[row * 32 + 16 + cm];
            }
        }
#pragma unroll
        for (int k = 0; k < 8; ++k) {
            if (role) {
                WB[g][k].x = 0.f; WB[g][k].y = 0.f;
            } else {
                const int e0 = (j + k * d2) & 15;
                const int e1 = (j + d1 + k * d2) & 15;
                WB[g][k].x = Whh0[row * 16 + e0];
                WB[g][k].y = Whh0[row * 16 + e1];
            }
        }
    }
    if (role) {
        b_r  = bih1[j]      + bhh1[j];
        b_z  = bih1[16 + j] + bhh1[16 + j];
        b_in = bih1[32 + j];
        b_hn = bhh1[32 + j];
    } else {
        b_r  = bih0[j]      + bhh0[j];
        b_z  = bih0[16 + j] + bhh0[16 + j];
        b_in = bih0[32 + j];
        b_hn = bhh0[32 + j];
    }

    float hs = 0.f;
    const float* xbase = x + (size_t)b * T_LEN * 32;

    float xl[4], xh[4];
#pragma unroll
    for (int k = 0; k < 4; ++k) {
        xl[k] = xbase[k * 32 + j];
        xh[k] = xbase[k * 32 + 16 + j];
    }

    auto step = [&](int i, int slot) {
        const float us = __shfl_xor(hs, 16, 64);
        const float x0 = xl[slot], x1 = xh[slot];
        const int t4 = (i + 4 < T_LEN) ? (i + 4) : (T_LEN - 1);
        xl[slot] = xbase[t4 * 32 + j];
        xh[slot] = xbase[t4 * 32 + 16 + j];

        v2f pA;
        pA.x = role ? us : x0;
        pA.y = role ? hs : x1;
        v2f pB;
        pB.x = hs;
        pB.y = rotf<0x121>(hs);

        v2f aA0 = {0.f,0.f}, aA1 = {0.f,0.f}, aA2 = {0.f,0.f};
        v2f aB0 = {0.f,0.f}, aB1 = {0.f,0.f}, aB2 = {0.f,0.f};
#pragma unroll
        for (int m = 0; m < 16; ++m) {
            pk_acc(aA0, WA[0][m], pA);
            pk_acc(aA1, WA[1][m], pA);
            pk_acc(aA2, WA[2][m], pA);
            if (m < 8) {
                pk_acc(aB0, WB[0][m], pB);
                pk_acc(aB1, WB[1][m], pB);
                pk_acc(aB2, WB[2][m], pB);
                if (m < 7) { pB.x = rotf<0x122>(pB.x); pB.y = rotf<0x122>(pB.y); }
            }
            if (m < 15) { pA.x = rotf<0x121>(pA.x); pA.y = rotf<0x121>(pA.y); }
        }

        const float pre_r = aA0.x + aA0.y + aB0.x + aB0.y + b_r;
        const float pre_z = aA1.x + aA1.y + aB1.x + aB1.y + b_z;
        const float xn_p = aA2.x + (role ? 0.f : aA2.y);
        const float hn_p = (role ? aA2.y : 0.f) + aB2.x + aB2.y;

        const float r = fsigm(pre_r);
        const float z = fsigm(pre_z);
        const float n = ftanh(xn_p + b_in + r * (hn_p + b_hn));
        hs = fmaf(z, hs - n, n);
    };

    step(0, 0);
    hs = role ? 0.f : hs;
#pragma unroll 1
    for (int i = 1; i <= T_LEN; ++i)
        step(i, i & 3);

    if (role) {
        float p = fcw[j] * hs;
        p += __shfl_xor(p, 1);
        p += __shfl_xor(p, 2);
        p += __shfl_xor(p, 4);
        p += __shfl_xor(p, 8);
        if (j == 0) out[b] = p + fcb[0];
    }
}

extern "C" void kernel_launch(void* const* d_in, const int* in_sizes, int n_in,
                              void* d_out, int out_size, void* d_ws, size_t ws_size,
                              hipStream_t stream) {
    const float* x    = (const float*)d_in[0];
    const float* Wih0 = (const float*)d_in[1];
    const float* Whh0 = (const float*)d_in[2];
    const float* bih0 = (const float*)d_in[3];
    const float* bhh0 = (const float*)d_in[4];
    const float* Wih1 = (const float*)d_in[5];
    const float* Whh1 = (const float*)d_in[6];
    const float* bih1 = (const float*)d_in[7];
    const float* bhh1 = (const float*)d_in[8];
    const float* fcw  = (const float*)d_in[9];
    const float* fcb  = (const float*)d_in[10];

    if (ws_size >= WS_NEEDED) {
        xg_gemm16<<<256, 256, 0, stream>>>(x, Wih0, bih0, d_ws);
        gru2_v2<<<256, 256, 0, stream>>>(d_ws, Whh0, bhh0, Wih1, Whh1,
                                         bih1, bhh1, fcw, fcb, (float*)d_out);
    } else {
        gru2_merged<<<256, 256, 0, stream>>>(x, Wih0, Whh0, bih0, bhh0,
                                             Wih1, Whh1, bih1, bhh1, fcw, fcb,
                                             (float*)d_out);
    }
}

// Round 12
// 243.273 us; speedup vs baseline: 2.3958x; 1.0564x over previous
//
#include <hip/hip_runtime.h>

static constexpr int T_LEN = 512;

typedef float v2f __attribute__((ext_vector_type(2)));
typedef _Float16 hh2 __attribute__((ext_vector_type(2)));

__device__ __forceinline__ float fsigm(float x) {
    return __builtin_amdgcn_rcpf(1.0f + __expf(-x));
}
__device__ __forceinline__ float ftanh(float x) {
    return 1.0f - 2.0f * __builtin_amdgcn_rcpf(1.0f + __expf(2.0f * x));
}
template <int CTRL>
__device__ __forceinline__ float rotf(float v) {
    return __builtin_bit_cast(float,
        __builtin_amdgcn_mov_dpp(__builtin_bit_cast(int, v), CTRL, 0xf, 0xf, true));
}
__device__ __forceinline__ void pk_acc(v2f& acc, v2f a, v2f b) {
    asm("v_pk_fma_f32 %0, %1, %2, %0" : "+v"(acc) : "v"(a), "v"(b));
}
__device__ __forceinline__ unsigned pkrz(float a, float b) {
    return __builtin_bit_cast(unsigned, __builtin_amdgcn_cvt_pkrtz(a, b));
}

// Producer/consumer fused GRU. Block = 3 waves, 4 batches:
//   wave 0 (producer): xg[t] = fp16(x[t] @ Wih0^T + bih0) for 4 batches,
//     16 lanes/batch, k-pairs (c, c+16), 16-hop DPP rot chain, NO serial
//     dependence -> never stalls on the recurrence. Writes an 8-slot LDS ring.
//   waves 1,2 (consumers): R9's merged-role recurrence (j=lane&15,
//     role=bit4: 0->L0, 1->L1 one step behind, bq=bit5->batch), reading xg
//     from the LDS ring. 48 v_pk_fma + 1 shfl per step, both layers.
// Sync: lgkm-only barrier once per 4-step group (producer one group ahead,
// alternating slot halves -> no read/write overlap). Global x prefetches
// stay in flight across barriers. 512 blocks x 3 waves = 1536 waves.
__global__ __launch_bounds__(192, 1) void gru2_pc(
    const float* __restrict__ x,
    const float* __restrict__ Wih0, const float* __restrict__ Whh0,
    const float* __restrict__ bih0, const float* __restrict__ bhh0,
    const float* __restrict__ Wih1, const float* __restrict__ Whh1,
    const float* __restrict__ bih1, const float* __restrict__ bhh1,
    const float* __restrict__ fcw,  const float* __restrict__ fcb,
    float* __restrict__ out)
{
    const int tid  = threadIdx.x;
    const int wv   = tid >> 6;        // 0 producer, 1-2 consumers
    const int lane = tid & 63;
    const int j    = lane & 15;
    const int b0   = blockIdx.x * 4;

    __shared__ unsigned       RZ[8][4][16];   // [slot][batch][unit] (r,z) f16x2
    __shared__ unsigned short NN[8][4][16];   // [slot][batch][unit] n f16

    const int d1 = (((int)rotf<0x121>((float)j)) - j) & 15;

    if (wv == 0) {
        // ================= producer =================
        const int bb = lane >> 4;     // batch 0..3
        v2f Wp[3][16];                // (Wih0[row][cm], Wih0[row][16+cm])
#pragma unroll
        for (int g = 0; g < 3; ++g) {
            const int row = g * 16 + j;
#pragma unroll
            for (int m = 0; m < 16; ++m) {
                const int cm = (j + m * d1) & 15;
                Wp[g][m].x = Wih0[row * 32 + cm];
                Wp[g][m].y = Wih0[row * 32 + 16 + cm];
            }
        }
        const float br = bih0[j], bz = bih0[16 + j], bn = bih0[32 + j];

        const float* xb = x + ((size_t)(b0 + bb) * T_LEN) * 32;
        // 4-deep prefetch ring: (x[t][j], x[t][16+j])
        float xa0 = xb[0*32 + j], xc0 = xb[0*32 + 16 + j];
        float xa1 = xb[1*32 + j], xc1 = xb[1*32 + 16 + j];
        float xa2 = xb[2*32 + j], xc2 = xb[2*32 + 16 + j];
        float xa3 = xb[3*32 + j], xc3 = xb[3*32 + 16 + j];

        auto prow = [&](float& xa, float& xc, int row) {
            v2f p; p.x = xa; p.y = xc;
            const int t4 = (row + 4 < T_LEN) ? (row + 4) : (T_LEN - 1);
            xa = xb[t4 * 32 + j];
            xc = xb[t4 * 32 + 16 + j];
            v2f a0 = {0.f,0.f}, a1 = {0.f,0.f}, a2 = {0.f,0.f};
#pragma unroll
            for (int m = 0; m < 16; ++m) {
                pk_acc(a0, Wp[0][m], p);
                pk_acc(a1, Wp[1][m], p);
                pk_acc(a2, Wp[2][m], p);
                if (m < 15) { p.x = rotf<0x121>(p.x); p.y = rotf<0x121>(p.y); }
            }
            RZ[row & 7][bb][j] = pkrz(a0.x + a0.y + br, a1.x + a1.y + bz);
            NN[row & 7][bb][j] = __builtin_bit_cast(unsigned short,
                                     (_Float16)(a2.x + a2.y + bn));
        };

#pragma unroll 1
        for (int G = 0; G < 129; ++G) {
            if (G < 128) {
                const int r0 = 4 * G;
                prow(xa0, xc0, r0);
                prow(xa1, xc1, r0 + 1);
                prow(xa2, xc2, r0 + 2);
                prow(xa3, xc3, r0 + 3);
            }
            asm volatile("s_waitcnt lgkmcnt(0)\n\ts_barrier" ::: "memory");
        }
    } else {
        // ================= consumer =================
        const int role = (lane >> 4) & 1;     // 0: layer0, 1: layer1 (lagged)
        const int bq   = lane >> 5;
        const int bb   = (wv - 1) * 2 + bq;   // batch 0..3
        const int b    = b0 + bb;

        v2f WA[3][16];
        float B_r, B_z, B_in, B_hn, rmask;
#pragma unroll
        for (int g = 0; g < 3; ++g) {
            const int row = g * 16 + j;
#pragma unroll
            for (int m = 0; m < 16; ++m) {
                const int cm = (j + m * d1) & 15;
                if (role) {
                    WA[g][m].x = Wih1[row * 16 + cm];
                    WA[g][m].y = Whh1[row * 16 + cm];
                } else {
                    const float w = Whh0[row * 16 + cm];
                    WA[g][m].x = (g == 2) ? 0.f : w;   // n-dot goes through .y
                    WA[g][m].y = (g == 2) ? w : 0.f;
                }
            }
        }
        if (role) {
            B_r = bih1[j] + bhh1[j];  B_z = bih1[16 + j] + bhh1[16 + j];
            B_in = bih1[32 + j];      B_hn = bhh1[32 + j];  rmask = 0.f;
        } else {
            B_r = bhh0[j];  B_z = bhh0[16 + j];
            B_in = 0.f;     B_hn = bhh0[32 + j];            rmask = 1.f;
        }

        float hs = 0.f;   // role0: h0_j ; role1: h1_j

        auto cstep = [&](unsigned rzv, unsigned nv) {
            const float us = __shfl_xor(hs, 16, 64);
            const hh2 rzh = __builtin_bit_cast(hh2, rzv);
            const float Xr = (float)rzh[0] * rmask;
            const float Xz = (float)rzh[1] * rmask;
            const float Xn = (float)__builtin_bit_cast(_Float16,
                                  (unsigned short)nv) * rmask;
            v2f p;
            p.x = role ? us : hs;
            p.y = hs;
            v2f a0 = {0.f,0.f}, a1 = {0.f,0.f}, a2 = {0.f,0.f};
#pragma unroll
            for (int m = 0; m < 16; ++m) {
                pk_acc(a0, WA[0][m], p);
                pk_acc(a1, WA[1][m], p);
                pk_acc(a2, WA[2][m], p);
                if (m < 15) { p.x = rotf<0x121>(p.x); p.y = rotf<0x121>(p.y); }
            }
            const float r = fsigm(Xr + a0.x + a0.y + B_r);
            const float z = fsigm(Xz + a1.x + a1.y + B_z);
            const float n = ftanh(Xn + a2.x + B_in + r * (a2.y + B_hn));
            hs = fmaf(z, hs - n, n);
        };

#pragma unroll 1
        for (int G = 0; G < 129; ++G) {
            if (G > 0) {
                const int r0 = 4 * (G - 1);
                const int s0 = r0 & 7;   // 0 or 4
                // batch the group's 8 LDS reads up front (hide ds latency)
                const unsigned z0 = RZ[s0    ][bb][j], n0 = NN[s0    ][bb][j];
                const unsigned z1 = RZ[s0 + 1][bb][j], n1 = NN[s0 + 1][bb][j];
                const unsigned z2 = RZ[s0 + 2][bb][j], n2 = NN[s0 + 2][bb][j];
                const unsigned z3 = RZ[s0 + 3][bb][j], n3 = NN[s0 + 3][bb][j];
                cstep(z0, n0);
                if (r0 == 0) hs = role ? 0.f : hs;  // role1's first step is garbage
                cstep(z1, n1);
                cstep(z2, n2);
                cstep(z3, n3);
            }
            asm volatile("s_waitcnt lgkmcnt(0)\n\ts_barrier" ::: "memory");
        }
        // epilogue: role1 computes h1[511] (us = h0[511]); role0 phantom.
        cstep(0u, 0u);

        // FC on final h1 (role1 lanes hold it distributed over j)
        if (role) {
            float pfc = fcw[j] * hs;
            pfc += __shfl_xor(pfc, 1, 64);
            pfc += __shfl_xor(pfc, 2, 64);
            pfc += __shfl_xor(pfc, 4, 64);
            pfc += __shfl_xor(pfc, 8, 64);
            if (j == 0) out[b] = pfc + fcb[0];
        }
    }
}

extern "C" void kernel_launch(void* const* d_in, const int* in_sizes, int n_in,
                              void* d_out, int out_size, void* d_ws, size_t ws_size,
                              hipStream_t stream) {
    const float* x    = (const float*)d_in[0];
    const float* Wih0 = (const float*)d_in[1];
    const float* Whh0 = (const float*)d_in[2];
    const float* bih0 = (const float*)d_in[3];
    const float* bhh0 = (const float*)d_in[4];
    const float* Wih1 = (const float*)d_in[5];
    const float* Whh1 = (const float*)d_in[6];
    const float* bih1 = (const float*)d_in[7];
    const float* bhh1 = (const float*)d_in[8];
    const float* fcw  = (const float*)d_in[9];
    const float* fcb  = (const float*)d_in[10];

    // 2048 batches / 4 per block -> 512 blocks x 3 waves (1P + 2C)
    gru2_pc<<<512, 192, 0, stream>>>(x, Wih0, Whh0, bih0, bhh0,
                                     Wih1, Whh1, bih1, bhh1, fcw, fcb,
                                     (float*)d_out);
}

// Round 13
// 183.465 us; speedup vs baseline: 3.1768x; 1.3260x over previous
//
#include <hip/hip_runtime.h>

static constexpr int T_LEN = 512;

typedef _Float16 h2 __attribute__((ext_vector_type(2)));

__device__ __forceinline__ float fsigm(float x) {
    return __builtin_amdgcn_rcpf(1.0f + __expf(-x));
}
__device__ __forceinline__ float ftanh(float x) {
    return 1.0f - 2.0f * __builtin_amdgcn_rcpf(1.0f + __expf(2.0f * x));
}
template <int CTRL>
__device__ __forceinline__ float rotf(float v) {
    return __builtin_bit_cast(float,
        __builtin_amdgcn_mov_dpp(__builtin_bit_cast(int, v), CTRL, 0xf, 0xf, true));
}
template <int CTRL>
__device__ __forceinline__ unsigned rotu(unsigned v) {
    return (unsigned)__builtin_amdgcn_mov_dpp((int)v, CTRL, 0xf, 0xf, true);
}
__device__ __forceinline__ unsigned pk2(float a, float b) {
    return __builtin_bit_cast(unsigned, __builtin_amdgcn_cvt_pkrtz(a, b));
}
// 2 f16 MACs, f32 accumulate, single-VGPR operands (no pair alignment!)
__device__ __forceinline__ float dot2(float acc, unsigned w, unsigned p) {
    asm("v_dot2_f32_f16 %0, %1, %2, %0" : "+v"(acc) : "v"(w), "v"(p));
    return acc;
}

// R5's validated fused structure + dot2 engine.
// Block = 4 waves, 8 batches. Waves 0,1: layer-0 (16 lanes/batch, lane j owns
// unit j, fp32 state, f16 packed operands). Waves 2,3: layer-1, one 4-step
// group behind, h0 handoff via 8-slot LDS ring (4 KB), lgkm-only barrier per
// group (global x prefetches stay in flight).
// Dots are DPP-systolic over PACKED f16 pairs:
//   L0 x-dot : pair (x[c], x[c+16]),  16 hops, 3 acc  -> 48 dot2, 15 DPP
//   L0 h-dot : pair (h[c], h[c+8]),    8 hops, 3 acc  -> 24 dot2,  7 DPP
//   L1       : pairs (h0[c],h0[c+8]) + (h1[c],h1[c+8]), 8 hops, dual streams
//              -> 48 dot2, 14 DPP
// Accumulators init = biases; n-gate keeps x-part / h-part separate for r*hn.
__global__ __launch_bounds__(256, 1) void gru2_dot(
    const float* __restrict__ x,
    const float* __restrict__ Wih0, const float* __restrict__ Whh0,
    const float* __restrict__ bih0, const float* __restrict__ bhh0,
    const float* __restrict__ Wih1, const float* __restrict__ Whh1,
    const float* __restrict__ bih1, const float* __restrict__ bhh1,
    const float* __restrict__ fcw,  const float* __restrict__ fcb,
    float* __restrict__ out)
{
    const int tid  = threadIdx.x;
    const int w    = tid >> 6;                   // wave 0..3
    const int lane = tid & 63;
    const int j    = lane & 15;                  // unit index
    const int bb   = (w & 1) * 4 + (lane >> 4);  // batch-in-block 0..7
    const int b    = blockIdx.x * 8 + bb;
    const bool isL0 = (w < 2);

    __shared__ float h0buf[8][8][16];            // [slot][bb][j]

    // rotation-direction probe
    const int d1 = (((int)rotf<0x121>((float)j)) - j) & 15;

    // ---- f16-pair weights (1 VGPR each) ----
    unsigned WX[3][16];   // L0 only: (Wih0[row][c], Wih0[row][16+c])
    unsigned WH[3][8];    // L0: (Whh0[row][c], Whh0[row][c+8]) ; L1: same of Whh1
    unsigned WI[3][8];    // L1 only: (Wih1[row][c], Wih1[row][c+8])
    float B_r, B_z, B_in, B_hn;

    if (isL0) {
#pragma unroll
        for (int g = 0; g < 3; ++g) {
            const int row = g * 16 + j;
#pragma unroll
            for (int m = 0; m < 16; ++m) {
                const int c = (j + m * d1) & 15;
                WX[g][m] = pk2(Wih0[row * 32 + c], Wih0[row * 32 + 16 + c]);
            }
#pragma unroll
            for (int m = 0; m < 8; ++m) {
                const int c = (j + m * d1) & 15;
                const int c8 = (c + 8) & 15;
                WH[g][m] = pk2(Whh0[row * 16 + c], Whh0[row * 16 + c8]);
            }
        }
        B_r  = bih0[j]      + bhh0[j];
        B_z  = bih0[16 + j] + bhh0[16 + j];
        B_in = bih0[32 + j];
        B_hn = bhh0[32 + j];
    } else {
#pragma unroll
        for (int g = 0; g < 3; ++g) {
            const int row = g * 16 + j;
#pragma unroll
            for (int m = 0; m < 8; ++m) {
                const int c = (j + m * d1) & 15;
                const int c8 = (c + 8) & 15;
                WI[g][m] = pk2(Wih1[row * 16 + c], Wih1[row * 16 + c8]);
                WH[g][m] = pk2(Whh1[row * 16 + c], Whh1[row * 16 + c8]);
            }
        }
        B_r  = bih1[j]      + bhh1[j];
        B_z  = bih1[16 + j] + bhh1[16 + j];
        B_in = bih1[32 + j];
        B_hn = bhh1[32 + j];
    }

    float hs = 0.f;                          // L0: h0_j ; L1: h1_j (fp32)

    // ---- x ring (L0 waves): 2 f32/step, 4 steps deep; xpf tracks row 4g ----
    const float* xpf = x + (size_t)b * T_LEN * 32;
    float xa0, xh0, xa1, xh1, xa2, xh2, xa3, xh3;
    if (isL0) {
        xa0 = xpf[0 * 32 + j];  xh0 = xpf[0 * 32 + 16 + j];
        xa1 = xpf[1 * 32 + j];  xh1 = xpf[1 * 32 + 16 + j];
        xa2 = xpf[2 * 32 + j];  xh2 = xpf[2 * 32 + 16 + j];
        xa3 = xpf[3 * 32 + j];  xh3 = xpf[3 * 32 + 16 + j];
    }

    float* const lbase = &h0buf[0][bb][j];

    auto l0_step = [&](float& xa, float& xh, int k, float* lw) {
        unsigned p = pk2(xa, xh);
        // prefetch row (4g + 4 + k): imm-offset loads off the bumped pointer
        xa = xpf[(4 + k) * 32 + j];
        xh = xpf[(4 + k) * 32 + 16 + j];

        float ar = B_r, az = B_z, an = B_in, hn = B_hn;
#pragma unroll
        for (int m = 0; m < 16; ++m) {
            ar = dot2(ar, WX[0][m], p);
            az = dot2(az, WX[1][m], p);
            an = dot2(an, WX[2][m], p);
            if (m < 15) p = rotu<0x121>(p);
        }
        unsigned q = pk2(hs, rotf<0x128>(hs));
#pragma unroll
        for (int m = 0; m < 8; ++m) {
            ar = dot2(ar, WH[0][m], q);
            az = dot2(az, WH[1][m], q);
            hn = dot2(hn, WH[2][m], q);
            if (m < 7) q = rotu<0x121>(q);
        }
        const float r = fsigm(ar);
        const float z = fsigm(az);
        const float n = ftanh(an + r * hn);
        hs = fmaf(z, hs - n, n);
        *lw = hs;
    };

    auto l1_step = [&](float u) {
        unsigned p0 = pk2(u, rotf<0x128>(u));     // (h0[c], h0[c+8])
        unsigned p1 = pk2(hs, rotf<0x128>(hs));   // (h1[c], h1[c+8])
        float ar = B_r, az = B_z, axn = B_in, ahn = B_hn;
#pragma unroll
        for (int m = 0; m < 8; ++m) {
            ar  = dot2(ar,  WI[0][m], p0);
            ar  = dot2(ar,  WH[0][m], p1);
            az  = dot2(az,  WI[1][m], p0);
            az  = dot2(az,  WH[1][m], p1);
            axn = dot2(axn, WI[2][m], p0);
            ahn = dot2(ahn, WH[2][m], p1);
            if (m < 7) { p0 = rotu<0x121>(p0); p1 = rotu<0x121>(p1); }
        }
        const float r = fsigm(ar);
        const float z = fsigm(az);
        const float n = ftanh(axn + r * ahn);
        hs = fmaf(z, hs - n, n);
    };

    // ---- pipelined loop: L0 does group g (rows 4g..4g+3, slots (4g&7)+k),
    // L1 does group g-1. One lgkm-only barrier per group. ----
#pragma unroll 1
    for (int g = 0; g < 129; ++g) {
        if (isL0) {
            if (g < 128) {
                float* lw = lbase + ((g & 1) ? 4 : 0) * 128;
                l0_step(xa0, xh0, 0, lw + 0 * 128);
                l0_step(xa1, xh1, 1, lw + 1 * 128);
                l0_step(xa2, xh2, 2, lw + 2 * 128);
                l0_step(xa3, xh3, 3, lw + 3 * 128);
                xpf += (g < 126) ? 128 : 0;   // last groups re-read in-bounds
            }
        } else {
            if (g > 0) {
                const float* lr = lbase + ((g & 1) ? 0 : 4) * 128;
                const float u0 = lr[0 * 128];
                const float u1 = lr[1 * 128];
                const float u2 = lr[2 * 128];
                const float u3 = lr[3 * 128];
                l1_step(u0);
                l1_step(u1);
                l1_step(u2);
                l1_step(u3);
            }
        }
        // LDS-visibility barrier WITHOUT vmcnt drain (x prefetches live on)
        asm volatile("s_waitcnt lgkmcnt(0)\n\ts_barrier" ::: "memory");
    }

    // ---- FC on final h1 (L1 waves hold it distributed over j) ----
    if (!isL0) {
        float p = fcw[j] * hs;
        p += __shfl_xor(p, 1);
        p += __shfl_xor(p, 2);
        p += __shfl_xor(p, 4);
        p += __shfl_xor(p, 8);
        if (j == 0) out[b] = p + fcb[0];
    }
}

extern "C" void kernel_launch(void* const* d_in, const int* in_sizes, int n_in,
                              void* d_out, int out_size, void* d_ws, size_t ws_size,
                              hipStream_t stream) {
    const float* x    = (const float*)d_in[0];
    const float* Wih0 = (const float*)d_in[1];
    const float* Whh0 = (const float*)d_in[2];
    const float* bih0 = (const float*)d_in[3];
    const float* bhh0 = (const float*)d_in[4];
    const float* Wih1 = (const float*)d_in[5];
    const float* Whh1 = (const float*)d_in[6];
    const float* bih1 = (const float*)d_in[7];
    const float* bhh1 = (const float*)d_in[8];
    const float* fcw  = (const float*)d_in[9];
    const float* fcb  = (const float*)d_in[10];

    // 2048 batches, 8 per block -> 256 blocks x 256 threads
    gru2_dot<<<256, 256, 0, stream>>>(x, Wih0, Whh0, bih0, bhh0,
                                      Wih1, Whh1, bih1, bhh1, fcw, fcb,
                                      (float*)d_out);
}

// Round 14
// 150.946 us; speedup vs baseline: 3.8612x; 1.2154x over previous
//
#include <hip/hip_runtime.h>

static constexpr int T_LEN = 512;

__device__ __forceinline__ float fsigm(float x) {
    return __builtin_amdgcn_rcpf(1.0f + __expf(-x));
}
__device__ __forceinline__ float ftanh(float x) {
    return 1.0f - 2.0f * __builtin_amdgcn_rcpf(1.0f + __expf(2.0f * x));
}
template <int CTRL>
__device__ __forceinline__ float rotf(float v) {
    return __builtin_bit_cast(float,
        __builtin_amdgcn_mov_dpp(__builtin_bit_cast(int, v), CTRL, 0xf, 0xf, true));
}
template <int CTRL>
__device__ __forceinline__ unsigned rotu(unsigned v) {
    return (unsigned)__builtin_amdgcn_mov_dpp((int)v, CTRL, 0xf, 0xf, true);
}
__device__ __forceinline__ unsigned pk2(float a, float b) {
    return __builtin_bit_cast(unsigned, __builtin_amdgcn_cvt_pkrtz(a, b));
}
__device__ __forceinline__ float dot2(float acc, unsigned w, unsigned p) {
    asm("v_dot2_f32_f16 %0, %1, %2, %0" : "+v"(acc) : "v"(w), "v"(p));
    return acc;
}

// R13 dot2 engine + load balance + 8-step groups.
// Block = 4 waves, 8 batches. Waves 0,1: layer-0; waves 2,3: layer-1 one
// 8-step group behind (h0 via 16-slot LDS ring, lgkm-only barrier per group).
// BALANCE: rows 8G+6, 8G+7's x-dots are computed by the L1 waves one group
// ahead (independent work; f32 via LDS, same summation order -> bit-exact
// vs R13). Per 8-step group both wave types issue 480 dot2.
__global__ __launch_bounds__(256, 1) void gru2_bal(
    const float* __restrict__ x,
    const float* __restrict__ Wih0, const float* __restrict__ Whh0,
    const float* __restrict__ bih0, const float* __restrict__ bhh0,
    const float* __restrict__ Wih1, const float* __restrict__ Whh1,
    const float* __restrict__ bih1, const float* __restrict__ bhh1,
    const float* __restrict__ fcw,  const float* __restrict__ fcb,
    float* __restrict__ out)
{
    const int tid  = threadIdx.x;
    const int w    = tid >> 6;
    const int lane = tid & 63;
    const int j    = lane & 15;
    const int bb   = (w & 1) * 4 + (lane >> 4);
    const int b    = blockIdx.x * 8 + bb;
    const bool isL0 = (w < 2);

    __shared__ float h0buf[16][8][16];        // 8 KB: [row&15][bb][j]
    __shared__ float xgbuf[2][2][3][8][16];   // 6 KB: [Gpar][row&1][gate][bb][j]

    const int d1 = (((int)rotf<0x121>((float)j)) - j) & 15;
    const float* xbase = x + (size_t)b * T_LEN * 32;

    if (isL0) {
        // ================= layer-0 waves =================
        unsigned WX[3][16], WH[3][8];
#pragma unroll
        for (int g = 0; g < 3; ++g) {
            const int row = g * 16 + j;
#pragma unroll
            for (int m = 0; m < 16; ++m) {
                const int c = (j + m * d1) & 15;
                WX[g][m] = pk2(Wih0[row * 32 + c], Wih0[row * 32 + 16 + c]);
            }
#pragma unroll
            for (int m = 0; m < 8; ++m) {
                const int c = (j + m * d1) & 15;
                WH[g][m] = pk2(Whh0[row * 16 + c], Whh0[row * 16 + ((c + 8) & 15)]);
            }
        }
        const float B_r  = bih0[j]      + bhh0[j];
        const float B_z  = bih0[16 + j] + bhh0[16 + j];
        const float B_in = bih0[32 + j];
        const float B_hn = bhh0[32 + j];

        float hs = 0.f;

        // x ring: slots 0..5 steady (rows 8G+0..5); temps for rows 6,7 (G=0)
        float xa0 = xbase[0*32+j], xh0 = xbase[0*32+16+j];
        float xa1 = xbase[1*32+j], xh1 = xbase[1*32+16+j];
        float xa2 = xbase[2*32+j], xh2 = xbase[2*32+16+j];
        float xa3 = xbase[3*32+j], xh3 = xbase[3*32+16+j];
        float xa4 = xbase[4*32+j], xh4 = xbase[4*32+16+j];
        float xa5 = xbase[5*32+j], xh5 = xbase[5*32+16+j];
        float xa6 = xbase[6*32+j], xh6 = xbase[6*32+16+j];
        float xa7 = xbase[7*32+j], xh7 = xbase[7*32+16+j];

        auto heavy = [&](float& xa, float& xh, int row) {
            unsigned p = pk2(xa, xh);
            int pr = row + 8; if (pr > T_LEN - 1) pr = T_LEN - 1;
            xa = xbase[pr * 32 + j];
            xh = xbase[pr * 32 + 16 + j];
            float ar = B_r, az = B_z, an = B_in, hn = B_hn;
#pragma unroll
            for (int m = 0; m < 16; ++m) {
                ar = dot2(ar, WX[0][m], p);
                az = dot2(az, WX[1][m], p);
                an = dot2(an, WX[2][m], p);
                if (m < 15) p = rotu<0x121>(p);
            }
            unsigned q = pk2(hs, rotf<0x128>(hs));
#pragma unroll
            for (int m = 0; m < 8; ++m) {
                ar = dot2(ar, WH[0][m], q);
                az = dot2(az, WH[1][m], q);
                hn = dot2(hn, WH[2][m], q);
                if (m < 7) q = rotu<0x121>(q);
            }
            const float r = fsigm(ar);
            const float z = fsigm(az);
            const float n = ftanh(an + r * hn);
            hs = fmaf(z, hs - n, n);
            h0buf[row & 15][bb][j] = hs;
        };
        auto light = [&](int row) {   // x-part precomputed by L1 waves
            const int par = (row >> 3) & 1, rb = row & 1;
            float ar = xgbuf[par][rb][0][bb][j];
            float az = xgbuf[par][rb][1][bb][j];
            float an = xgbuf[par][rb][2][bb][j];
            float hn = B_hn;
            unsigned q = pk2(hs, rotf<0x128>(hs));
#pragma unroll
            for (int m = 0; m < 8; ++m) {
                ar = dot2(ar, WH[0][m], q);
                az = dot2(az, WH[1][m], q);
                hn = dot2(hn, WH[2][m], q);
                if (m < 7) q = rotu<0x121>(q);
            }
            const float r = fsigm(ar);
            const float z = fsigm(az);
            const float n = ftanh(an + r * hn);
            hs = fmaf(z, hs - n, n);
            h0buf[row & 15][bb][j] = hs;
        };

        // G = 0: all 8 rows heavy (no precomputed xg yet)
        heavy(xa0, xh0, 0); heavy(xa1, xh1, 1); heavy(xa2, xh2, 2);
        heavy(xa3, xh3, 3); heavy(xa4, xh4, 4); heavy(xa5, xh5, 5);
        heavy(xa6, xh6, 6); heavy(xa7, xh7, 7);
        asm volatile("s_waitcnt lgkmcnt(0)\n\ts_barrier" ::: "memory");

#pragma unroll 1
        for (int G = 1; G < 64; ++G) {
            const int r0 = 8 * G;
            heavy(xa0, xh0, r0 + 0);
            heavy(xa1, xh1, r0 + 1);
            heavy(xa2, xh2, r0 + 2);
            heavy(xa3, xh3, r0 + 3);
            heavy(xa4, xh4, r0 + 4);
            heavy(xa5, xh5, r0 + 5);
            light(r0 + 6);
            light(r0 + 7);
            asm volatile("s_waitcnt lgkmcnt(0)\n\ts_barrier" ::: "memory");
        }
        // G = 64: L0 idle, match barrier count
        asm volatile("s_waitcnt lgkmcnt(0)\n\ts_barrier" ::: "memory");
    } else {
        // ================= layer-1 waves =================
        unsigned WI[3][8], WHr[3][8], WX[3][16];
#pragma unroll
        for (int g = 0; g < 3; ++g) {
            const int row = g * 16 + j;
#pragma unroll
            for (int m = 0; m < 8; ++m) {
                const int c = (j + m * d1) & 15;
                const int c8 = (c + 8) & 15;
                WI[g][m]  = pk2(Wih1[row * 16 + c], Wih1[row * 16 + c8]);
                WHr[g][m] = pk2(Whh1[row * 16 + c], Whh1[row * 16 + c8]);
            }
#pragma unroll
            for (int m = 0; m < 16; ++m) {
                const int c = (j + m * d1) & 15;
                WX[g][m] = pk2(Wih0[row * 32 + c], Wih0[row * 32 + 16 + c]);
            }
        }
        const float B_r  = bih1[j]      + bhh1[j];
        const float B_z  = bih1[16 + j] + bhh1[16 + j];
        const float B_in = bih1[32 + j];
        const float B_hn = bhh1[32 + j];
        const float BX_r = bih0[j]      + bhh0[j];
        const float BX_z = bih0[16 + j] + bhh0[16 + j];
        const float BX_n = bih0[32 + j];

        float hs = 0.f;

        // x ring for transferred rows: current pair = rows 8(G+1)+{6,7}
        float ya0 = xbase[14 * 32 + j], yh0 = xbase[14 * 32 + 16 + j];
        float ya1 = xbase[15 * 32 + j], yh1 = xbase[15 * 32 + 16 + j];

        auto l1_step = [&](float u) {
            unsigned p0 = pk2(u,  rotf<0x128>(u));
            unsigned p1 = pk2(hs, rotf<0x128>(hs));
            float ar = B_r, az = B_z, axn = B_in, ahn = B_hn;
#pragma unroll
            for (int m = 0; m < 8; ++m) {
                ar  = dot2(ar,  WI[0][m],  p0);
                ar  = dot2(ar,  WHr[0][m], p1);
                az  = dot2(az,  WI[1][m],  p0);
                az  = dot2(az,  WHr[1][m], p1);
                axn = dot2(axn, WI[2][m],  p0);
                ahn = dot2(ahn, WHr[2][m], p1);
                if (m < 7) { p0 = rotu<0x121>(p0); p1 = rotu<0x121>(p1); }
            }
            const float r = fsigm(ar);
            const float z = fsigm(az);
            const float n = ftanh(axn + r * ahn);
            hs = fmaf(z, hs - n, n);
        };
        auto l1_xg = [&](float xa, float xh, int row) {
            unsigned p = pk2(xa, xh);
            float ar = BX_r, az = BX_z, an = BX_n;
#pragma unroll
            for (int m = 0; m < 16; ++m) {
                ar = dot2(ar, WX[0][m], p);
                az = dot2(az, WX[1][m], p);
                an = dot2(an, WX[2][m], p);
                if (m < 15) p = rotu<0x121>(p);
            }
            const int par = (row >> 3) & 1, rb = row & 1;
            xgbuf[par][rb][0][bb][j] = ar;
            xgbuf[par][rb][1][bb][j] = az;
            xgbuf[par][rb][2][bb][j] = an;
        };

        // G = 0: no recurrence yet; produce xg rows 14,15; prefetch 22,23
        l1_xg(ya0, yh0, 14);
        l1_xg(ya1, yh1, 15);
        ya0 = xbase[22 * 32 + j];  yh0 = xbase[22 * 32 + 16 + j];
        ya1 = xbase[23 * 32 + j];  yh1 = xbase[23 * 32 + 16 + j];
        asm volatile("s_waitcnt lgkmcnt(0)\n\ts_barrier" ::: "memory");

#pragma unroll 1
        for (int G = 1; G < 64; ++G) {
            const int r0 = 8 * (G - 1);
            const int s0 = r0 & 15;
            // batch the 8 h0 reads (pipelined ds_reads)
            const float u0 = h0buf[s0 + 0][bb][j];
            const float u1 = h0buf[s0 + 1][bb][j];
            const float u2 = h0buf[s0 + 2][bb][j];
            const float u3 = h0buf[s0 + 3][bb][j];
            const float u4 = h0buf[s0 + 4][bb][j];
            const float u5 = h0buf[s0 + 5][bb][j];
            const float u6 = h0buf[s0 + 6][bb][j];
            const float u7 = h0buf[s0 + 7][bb][j];
            l1_step(u0); l1_step(u1); l1_step(u2); l1_step(u3);
            l1_step(u4); l1_step(u5); l1_step(u6); l1_step(u7);
            if (G <= 62) {
                const int rx = 8 * (G + 1) + 6;
                l1_xg(ya0, yh0, rx);
                l1_xg(ya1, yh1, rx + 1);
                int pr = 8 * (G + 2) + 6;
                if (pr > T_LEN - 2) pr = T_LEN - 2;
                ya0 = xbase[pr * 32 + j];       yh0 = xbase[pr * 32 + 16 + j];
                ya1 = xbase[(pr + 1) * 32 + j]; yh1 = xbase[(pr + 1) * 32 + 16 + j];
            }
            asm volatile("s_waitcnt lgkmcnt(0)\n\ts_barrier" ::: "memory");
        }
        // G = 64: final recurrence group (rows 504..511)
        {
            const int s0 = 504 & 15;   // = 8
            const float u0 = h0buf[s0 + 0][bb][j];
            const float u1 = h0buf[s0 + 1][bb][j];
            const float u2 = h0buf[s0 + 2][bb][j];
            const float u3 = h0buf[s0 + 3][bb][j];
            const float u4 = h0buf[s0 + 4][bb][j];
            const float u5 = h0buf[s0 + 5][bb][j];
            const float u6 = h0buf[s0 + 6][bb][j];
            const float u7 = h0buf[s0 + 7][bb][j];
            l1_step(u0); l1_step(u1); l1_step(u2); l1_step(u3);
            l1_step(u4); l1_step(u5); l1_step(u6); l1_step(u7);
        }
        asm volatile("s_waitcnt lgkmcnt(0)\n\ts_barrier" ::: "memory");

        // FC on final h1 (distributed over j)
        float p = fcw[j] * hs;
        p += __shfl_xor(p, 1);
        p += __shfl_xor(p, 2);
        p += __shfl_xor(p, 4);
        p += __shfl_xor(p, 8);
        if (j == 0) out[b] = p + fcb[0];
    }
}

extern "C" void kernel_launch(void* const* d_in, const int* in_sizes, int n_in,
                              void* d_out, int out_size, void* d_ws, size_t ws_size,
                              hipStream_t stream) {
    const float* x    = (const float*)d_in[0];
    const float* Wih0 = (const float*)d_in[1];
    const float* Whh0 = (const float*)d_in[2];
    const float* bih0 = (const float*)d_in[3];
    const float* bhh0 = (const float*)d_in[4];
    const float* Wih1 = (const float*)d_in[5];
    const float* Whh1 = (const float*)d_in[6];
    const float* bih1 = (const float*)d_in[7];
    const float* bhh1 = (const float*)d_in[8];
    const float* fcw  = (const float*)d_in[9];
    const float* fcb  = (const float*)d_in[10];

    // 2048 batches, 8 per block -> 256 blocks x 256 threads
    gru2_bal<<<256, 256, 0, stream>>>(x, Wih0, Whh0, bih0, bhh0,
                                      Wih1, Whh1, bih1, bhh1, fcw, fcb,
                                      (float*)d_out);
}